// Round 3
// baseline (234.733 us; speedup 1.0000x reference)
//
#include <hip/hip_runtime.h>
#include <math.h>

#define N_PTS 131072
#define BPB   32                 // blocks per batch
#define CHUNK (N_PTS / BPB)      // 4096 elements per block
#define TPB   256
#define NACC  16                 // W, As[3], At[3], M[9]
#define NITER (CHUNK / 4 / TPB)  // 4 float4 per thread per stream

// ws layout: float sums[B][16] @0 (2048 B for B=32), int counters[B] @2048
#define WS_SUMS_FLOATS (32 * NACC)
#define WS_BYTES (WS_SUMS_FLOATS * 4 + 32 * 4)

__device__ void ego_solve(const double* acc, float* out, int b, int B);

// ---------------- Fused kernel: reduce + atomic combine + last-block SVD ---
__global__ __launch_bounds__(TPB) void ego_fused_kernel(
    const float* __restrict__ xyz_s,    // (B,3,N)
    const float* __restrict__ wtgt,     // (B,3,N)
    const float* __restrict__ weights,  // (B,1,N)
    const float* __restrict__ label,    // (B,1,N)
    float* __restrict__ sums,           // (B,16) zeroed
    int*   __restrict__ counters,       // (B)    zeroed
    float* __restrict__ out, int B)
{
    const int b     = blockIdx.y;
    const int chunk = blockIdx.x;
    const int t     = threadIdx.x;

    const size_t baseN  = (size_t)b * N_PTS + (size_t)chunk * CHUNK;
    const size_t base3  = (size_t)b * 3 * N_PTS + (size_t)chunk * CHUNK;

    const float4* w4  = (const float4*)(weights + baseN);
    const float4* l4  = (const float4*)(label   + baseN);
    const float4* xs0 = (const float4*)(xyz_s + base3);
    const float4* xs1 = (const float4*)(xyz_s + base3 + N_PTS);
    const float4* xs2 = (const float4*)(xyz_s + base3 + 2 * N_PTS);
    const float4* xt0 = (const float4*)(wtgt  + base3);
    const float4* xt1 = (const float4*)(wtgt  + base3 + N_PTS);
    const float4* xt2 = (const float4*)(wtgt  + base3 + 2 * N_PTS);

    float acc[NACC];
#pragma unroll
    for (int i = 0; i < NACC; ++i) acc[i] = 0.0f;

    // 2-deep register ping-pong pipeline over NITER=4 iterations
    float4 wvA, lvA, a0A, a1A, a2A, b0A, b1A, b2A;
    float4 wvB, lvB, a0B, a1B, a2B, b0B, b1B, b2B;

#define LOADBUF(S, k)                                    \
    {   const int i_ = t + (k) * TPB;                    \
        wv##S = w4[i_];  lv##S = l4[i_];                 \
        a0##S = xs0[i_]; a1##S = xs1[i_]; a2##S = xs2[i_]; \
        b0##S = xt0[i_]; b1##S = xt1[i_]; b2##S = xt2[i_]; }

#define ACCUM1(S, C)                                          \
        {                                                     \
            const float w  = wv##S.C * fabsf(lv##S.C - 1.0f); \
            const float s0 = a0##S.C, s1 = a1##S.C, s2 = a2##S.C; \
            const float t0 = b0##S.C, t1 = b1##S.C, t2 = b2##S.C; \
            acc[0] += w;                                      \
            const float ws0 = w * s0, ws1 = w * s1, ws2 = w * s2; \
            acc[1] += ws0;  acc[2] += ws1;  acc[3] += ws2;    \
            acc[4] += w * t0; acc[5] += w * t1; acc[6] += w * t2; \
            acc[7]  += ws0 * t0; acc[8]  += ws0 * t1; acc[9]  += ws0 * t2; \
            acc[10] += ws1 * t0; acc[11] += ws1 * t1; acc[12] += ws1 * t2; \
            acc[13] += ws2 * t0; acc[14] += ws2 * t1; acc[15] += ws2 * t2; \
        }
#define CONSUME(S) ACCUM1(S, x) ACCUM1(S, y) ACCUM1(S, z) ACCUM1(S, w)

    LOADBUF(A, 0)
    LOADBUF(B, 1)
    CONSUME(A)
    LOADBUF(A, 2)
    CONSUME(B)
    LOADBUF(B, 3)
    CONSUME(A)
    CONSUME(B)

#undef LOADBUF
#undef ACCUM1
#undef CONSUME

    // wave-level reduce (64 lanes)
#pragma unroll
    for (int i = 0; i < NACC; ++i) {
        float v = acc[i];
#pragma unroll
        for (int off = 32; off > 0; off >>= 1)
            v += __shfl_down(v, off, 64);
        acc[i] = v;
    }

    __shared__ float red[TPB / 64][NACC];
    const int wave = t >> 6;
    const int lane = t & 63;
    if (lane == 0) {
#pragma unroll
        for (int i = 0; i < NACC; ++i) red[wave][i] = acc[i];
    }
    __syncthreads();

    if (t < NACC) {
        float v = 0.0f;
#pragma unroll
        for (int wv_ = 0; wv_ < TPB / 64; ++wv_) v += red[wv_][t];
        atomicAdd(&sums[b * NACC + t], v);
    }

    // completion counter (release)
    __shared__ int is_last;
    if (t == 0) {
        __threadfence();
        const int old = atomicAdd(&counters[b], 1);
        is_last = (old == BPB - 1) ? 1 : 0;
    }
    __syncthreads();

    if (is_last && t == 0) {
        __threadfence();   // acquire
        double acc_d[NACC];
#pragma unroll
        for (int i = 0; i < NACC; ++i)
            acc_d[i] = (double)__hip_atomic_load(&sums[b * NACC + i],
                                                 __ATOMIC_ACQUIRE,
                                                 __HIP_MEMORY_SCOPE_AGENT);
        ego_solve(acc_d, out, b, B);
    }
}

// ---------------- per-batch 3x3 SVD Kabsch (single thread) ----------------
__device__ void ego_solve(const double* acc, float* out, int b, int B)
{
    const double W     = acc[0];
    const double denom = W + 1e-6;
    double cs[3], ct[3];
#pragma unroll
    for (int d = 0; d < 3; ++d) {
        cs[d] = acc[1 + d] / denom;
        ct[d] = acc[4 + d] / denom;
    }
    const double Wn = W / denom;

    double cov[3][3];
#pragma unroll
    for (int d = 0; d < 3; ++d)
#pragma unroll
        for (int e = 0; e < 3; ++e)
            cov[d][e] = acc[7 + d * 3 + e] / denom - cs[d] * ct[e] * (2.0 - Wn);

    // Bm = cov^T cov, Jacobi eigen-decomposition -> V, lambda
    double Bm[3][3];
    for (int i = 0; i < 3; ++i)
        for (int j = 0; j < 3; ++j) {
            double s = 0.0;
            for (int k = 0; k < 3; ++k) s += cov[k][i] * cov[k][j];
            Bm[i][j] = s;
        }
    double V[3][3] = {{1,0,0},{0,1,0},{0,0,1}};

    for (int sweep = 0; sweep < 8; ++sweep) {
        const int pq[3][2] = {{0,1},{0,2},{1,2}};
        for (int r = 0; r < 3; ++r) {
            const int pp = pq[r][0], qq = pq[r][1];
            const double apq = Bm[pp][qq];
            if (fabs(apq) < 1e-300) continue;
            const double tau = (Bm[qq][qq] - Bm[pp][pp]) / (2.0 * apq);
            const double tt  = (tau >= 0.0 ? 1.0 : -1.0) /
                               (fabs(tau) + sqrt(1.0 + tau * tau));
            const double c = 1.0 / sqrt(1.0 + tt * tt);
            const double s = tt * c;
            for (int k = 0; k < 3; ++k) {
                const double bkp = Bm[k][pp], bkq = Bm[k][qq];
                Bm[k][pp] = c * bkp - s * bkq;
                Bm[k][qq] = s * bkp + c * bkq;
            }
            for (int k = 0; k < 3; ++k) {
                const double bpk = Bm[pp][k], bqk = Bm[qq][k];
                Bm[pp][k] = c * bpk - s * bqk;
                Bm[qq][k] = s * bpk + c * bqk;
            }
            for (int k = 0; k < 3; ++k) {
                const double vkp = V[k][pp], vkq = V[k][qq];
                V[k][pp] = c * vkp - s * vkq;
                V[k][qq] = s * vkp + c * vkq;
            }
        }
    }

    double lam[3] = {Bm[0][0], Bm[1][1], Bm[2][2]};
    int idx[3] = {0, 1, 2};
    for (int i = 0; i < 2; ++i)
        for (int j = i + 1; j < 3; ++j)
            if (lam[idx[j]] > lam[idx[i]]) { int tmp = idx[i]; idx[i] = idx[j]; idx[j] = tmp; }
    double Vs[3][3];
    for (int c = 0; c < 3; ++c)
        for (int rr = 0; rr < 3; ++rr) Vs[rr][c] = V[rr][idx[c]];

    double U[3][3];
    for (int c = 0; c < 3; ++c) {
        double u0 = 0, u1 = 0, u2 = 0;
        for (int k = 0; k < 3; ++k) {
            u0 += cov[0][k] * Vs[k][c];
            u1 += cov[1][k] * Vs[k][c];
            u2 += cov[2][k] * Vs[k][c];
        }
        const double nn = sqrt(u0 * u0 + u1 * u1 + u2 * u2);
        if (nn > 1e-150) {
            U[0][c] = u0 / nn; U[1][c] = u1 / nn; U[2][c] = u2 / nn;
        } else if (c == 2) {
            U[0][2] = U[1][0] * U[2][1] - U[2][0] * U[1][1];
            U[1][2] = U[2][0] * U[0][1] - U[0][0] * U[2][1];
            U[2][2] = U[0][0] * U[1][1] - U[1][0] * U[0][1];
        } else {
            U[0][c] = (c == 0); U[1][c] = (c == 1); U[2][c] = 0.0;
        }
    }

    double rot[3][3];
    for (int d = 0; d < 3; ++d)
        for (int e = 0; e < 3; ++e)
            rot[d][e] = Vs[d][0] * U[e][0] + Vs[d][1] * U[e][1] + Vs[d][2] * U[e][2];

    const double det =
        rot[0][0] * (rot[1][1] * rot[2][2] - rot[1][2] * rot[2][1]) -
        rot[0][1] * (rot[1][0] * rot[2][2] - rot[1][2] * rot[2][0]) +
        rot[0][2] * (rot[1][0] * rot[2][1] - rot[1][1] * rot[2][0]);

    if (!(det > 0.0)) {
        for (int d = 0; d < 3; ++d)
            for (int e = 0; e < 3; ++e)
                rot[d][e] = Vs[d][0] * U[e][0] + Vs[d][1] * U[e][1] - Vs[d][2] * U[e][2];
    }

    double tr[3];
    for (int d = 0; d < 3; ++d)
        tr[d] = -(rot[d][0] * cs[0] + rot[d][1] * cs[1] + rot[d][2] * cs[2]) + ct[d];

    for (int d = 0; d < 3; ++d)
        for (int e = 0; e < 3; ++e)
            out[(size_t)b * 9 + d * 3 + e] = (float)rot[d][e];
    for (int d = 0; d < 3; ++d)
        out[(size_t)B * 9 + (size_t)b * 3 + d] = (float)tr[d];
}

extern "C" void kernel_launch(void* const* d_in, const int* in_sizes, int n_in,
                              void* d_out, int out_size, void* d_ws, size_t ws_size,
                              hipStream_t stream) {
    const float* xyz_s   = (const float*)d_in[0];
    const float* wtgt    = (const float*)d_in[1];
    const float* weights = (const float*)d_in[2];
    const float* label   = (const float*)d_in[3];
    float* out = (float*)d_out;

    float* sums     = (float*)d_ws;
    int*   counters = (int*)((char*)d_ws + WS_SUMS_FLOATS * 4);

    const int B = in_sizes[2] / N_PTS;   // weights has B*N elements

    hipMemsetAsync(d_ws, 0, WS_BYTES, stream);

    dim3 grid(BPB, B);
    ego_fused_kernel<<<grid, TPB, 0, stream>>>(xyz_s, wtgt, weights, label,
                                               sums, counters, out, B);
}

// Round 4
// 155.310 us; speedup vs baseline: 1.5114x; 1.5114x over previous
//
#include <hip/hip_runtime.h>
#include <math.h>

#define N_PTS 131072
#define BPB   64                 // blocks per batch (reduction chunks)
#define CHUNK (N_PTS / BPB)      // 2048 elements per block
#define TPB   256
#define NACC  16                 // W, As[3], At[3], M[9]
#define NITER (CHUNK / 4 / TPB)  // 2 float4 per thread per stream

// ---------------- Kernel 1: streaming partial reduction ----------------
__global__ __launch_bounds__(TPB) void ego_partial_kernel(
    const float* __restrict__ xyz_s,    // (B,3,N)
    const float* __restrict__ wtgt,     // (B,3,N)
    const float* __restrict__ weights,  // (B,1,N)
    const float* __restrict__ label,    // (B,1,N)
    float* __restrict__ partials)       // (B, BPB, 16)
{
    const int b     = blockIdx.y;
    const int chunk = blockIdx.x;
    const int t     = threadIdx.x;

    const size_t baseN  = (size_t)b * N_PTS + (size_t)chunk * CHUNK;
    const size_t base3  = (size_t)b * 3 * N_PTS + (size_t)chunk * CHUNK;

    const float4* w4  = (const float4*)(weights + baseN);
    const float4* l4  = (const float4*)(label   + baseN);
    const float4* xs0 = (const float4*)(xyz_s + base3);
    const float4* xs1 = (const float4*)(xyz_s + base3 + N_PTS);
    const float4* xs2 = (const float4*)(xyz_s + base3 + 2 * N_PTS);
    const float4* xt0 = (const float4*)(wtgt  + base3);
    const float4* xt1 = (const float4*)(wtgt  + base3 + N_PTS);
    const float4* xt2 = (const float4*)(wtgt  + base3 + 2 * N_PTS);

    float acc[NACC];
#pragma unroll
    for (int i = 0; i < NACC; ++i) acc[i] = 0.0f;

#pragma unroll
    for (int k = 0; k < NITER; ++k) {
        const int i = t + k * TPB;
        const float4 wv = w4[i];
        const float4 lv = l4[i];
        const float4 a0 = xs0[i], a1 = xs1[i], a2 = xs2[i];
        const float4 b0 = xt0[i], b1 = xt1[i], b2 = xt2[i];

#define ACCUM(C)                                              \
        {                                                     \
            const float w  = wv.C * fabsf(lv.C - 1.0f);       \
            const float s0 = a0.C, s1 = a1.C, s2 = a2.C;      \
            const float t0 = b0.C, t1 = b1.C, t2 = b2.C;      \
            acc[0] += w;                                      \
            const float ws0 = w * s0, ws1 = w * s1, ws2 = w * s2; \
            acc[1] += ws0;  acc[2] += ws1;  acc[3] += ws2;    \
            acc[4] += w * t0; acc[5] += w * t1; acc[6] += w * t2; \
            acc[7]  += ws0 * t0; acc[8]  += ws0 * t1; acc[9]  += ws0 * t2; \
            acc[10] += ws1 * t0; acc[11] += ws1 * t1; acc[12] += ws1 * t2; \
            acc[13] += ws2 * t0; acc[14] += ws2 * t1; acc[15] += ws2 * t2; \
        }
        ACCUM(x) ACCUM(y) ACCUM(z) ACCUM(w)
#undef ACCUM
    }

    // wave-level reduce (64 lanes)
#pragma unroll
    for (int i = 0; i < NACC; ++i) {
        float v = acc[i];
#pragma unroll
        for (int off = 32; off > 0; off >>= 1)
            v += __shfl_down(v, off, 64);
        acc[i] = v;
    }

    __shared__ float red[TPB / 64][NACC];
    const int wave = t >> 6;
    const int lane = t & 63;
    if (lane == 0) {
#pragma unroll
        for (int i = 0; i < NACC; ++i) red[wave][i] = acc[i];
    }
    __syncthreads();

    if (t < NACC) {
        float v = 0.0f;
#pragma unroll
        for (int wv_ = 0; wv_ < TPB / 64; ++wv_) v += red[wv_][t];
        partials[((size_t)b * BPB + chunk) * NACC + t] = v;
    }
}

// ---------------- Kernel 2: final reduce + scratch-free 3x3 SVD ----------
__global__ __launch_bounds__(64) void ego_finalize_kernel(
    const float* __restrict__ partials,  // (B, BPB, 16)
    float* __restrict__ out,             // rot (B,3,3) then translation (B,3,1)
    int B)
{
    const int b = blockIdx.x;
    const int t = threadIdx.x;   // 0..63 == BPB

    double acc[NACC];
    const float* p = partials + ((size_t)b * BPB + t) * NACC;
#pragma unroll
    for (int i = 0; i < NACC; ++i) acc[i] = (double)p[i];

#pragma unroll
    for (int i = 0; i < NACC; ++i) {
        double v = acc[i];
#pragma unroll
        for (int off = 32; off > 0; off >>= 1)
            v += __shfl_down(v, off, 64);
        acc[i] = v;
    }

    if (t != 0) return;

    // ---- all-scalar solve: no arrays, no dynamic indexing, no scratch ----
    const double W     = acc[0];
    const double denom = W + 1e-6;
    const double cs0 = acc[1] / denom, cs1 = acc[2] / denom, cs2 = acc[3] / denom;
    const double ct0 = acc[4] / denom, ct1 = acc[5] / denom, ct2 = acc[6] / denom;
    const double f   = 2.0 - W / denom;

    const double c00 = acc[7]  / denom - cs0 * ct0 * f;
    const double c01 = acc[8]  / denom - cs0 * ct1 * f;
    const double c02 = acc[9]  / denom - cs0 * ct2 * f;
    const double c10 = acc[10] / denom - cs1 * ct0 * f;
    const double c11 = acc[11] / denom - cs1 * ct1 * f;
    const double c12 = acc[12] / denom - cs1 * ct2 * f;
    const double c20 = acc[13] / denom - cs2 * ct0 * f;
    const double c21 = acc[14] / denom - cs2 * ct1 * f;
    const double c22 = acc[15] / denom - cs2 * ct2 * f;

    // Bm = cov^T cov (symmetric, 6 scalars)
    double b00 = c00*c00 + c10*c10 + c20*c20;
    double b01 = c00*c01 + c10*c11 + c20*c21;
    double b02 = c00*c02 + c10*c12 + c20*c22;
    double b11 = c01*c01 + c11*c11 + c21*c21;
    double b12 = c01*c02 + c11*c12 + c21*c22;
    double b22 = c02*c02 + c12*c12 + c22*c22;

    // V columns as scalars vRC (row R, col C)
    double v00 = 1, v01 = 0, v02 = 0;
    double v10 = 0, v11 = 1, v12 = 0;
    double v20 = 0, v21 = 0, v22 = 1;

    // Jacobi rotation on pair (p,q); bkp/bkq couple the third index k.
#define JROT(bpp, bqq, bpq, bkp, bkq, vp0, vp1, vp2, vq0, vq1, vq2)   \
    if (fabs(bpq) > 1e-30) {                                          \
        const double tau = (bqq - bpp) / (2.0 * bpq);                 \
        const double jt  = (tau >= 0.0 ? 1.0 : -1.0) /                \
                           (fabs(tau) + sqrt(1.0 + tau * tau));       \
        const double jc  = 1.0 / sqrt(1.0 + jt * jt);                 \
        const double js  = jt * jc;                                   \
        bpp -= jt * bpq; bqq += jt * bpq; bpq = 0.0;                  \
        { const double kp = bkp, kq = bkq;                            \
          bkp = jc * kp - js * kq; bkq = js * kp + jc * kq; }         \
        { double x;                                                   \
          x = vp0; vp0 = jc * x - js * vq0; vq0 = js * x + jc * vq0;  \
          x = vp1; vp1 = jc * x - js * vq1; vq1 = js * x + jc * vq1;  \
          x = vp2; vp2 = jc * x - js * vq2; vq2 = js * x + jc * vq2; }\
    }

#pragma unroll
    for (int sweep = 0; sweep < 6; ++sweep) {
        JROT(b00, b11, b01, b02, b12, v00, v10, v20, v01, v11, v21)   // (0,1), k=2
        JROT(b00, b22, b02, b01, b12, v00, v10, v20, v02, v12, v22)   // (0,2), k=1
        JROT(b11, b22, b12, b01, b02, v01, v11, v21, v02, v12, v22)   // (1,2), k=0
    }
#undef JROT

    // sort eigen-pairs descending by eigenvalue (scalar cond-swaps)
    double l0 = b00, l1 = b11, l2 = b22;
#define CSWAP(la, lb, a0, a1, a2, q0, q1, q2)                         \
    if (lb > la) { double x;                                          \
        x = la; la = lb; lb = x;                                      \
        x = a0; a0 = q0; q0 = x;                                      \
        x = a1; a1 = q1; q1 = x;                                      \
        x = a2; a2 = q2; q2 = x; }
    CSWAP(l0, l1, v00, v10, v20, v01, v11, v21)
    CSWAP(l0, l2, v00, v10, v20, v02, v12, v22)
    CSWAP(l1, l2, v01, v11, v21, v02, v12, v22)
#undef CSWAP

    // U columns: u_c = cov * v_c, normalized
#define MAKEU(vc0, vc1, vc2, u0, u1, u2)                              \
    double u0 = c00 * vc0 + c01 * vc1 + c02 * vc2;                    \
    double u1 = c10 * vc0 + c11 * vc1 + c12 * vc2;                    \
    double u2 = c20 * vc0 + c21 * vc1 + c22 * vc2;                    \
    { const double nn = sqrt(u0 * u0 + u1 * u1 + u2 * u2);            \
      const double r = (nn > 1e-150) ? 1.0 / nn : 0.0;                \
      u0 *= r; u1 *= r; u2 *= r; }
    MAKEU(v00, v10, v20, u00, u10, u20)   // U column 0
    MAKEU(v01, v11, v21, u01, u11, u21)   // U column 1
    MAKEU(v02, v12, v22, u02, u12, u22)   // U column 2
#undef MAKEU
    // degenerate sigma_2 ~ 0: rebuild U col 2 as cross(Ucol0, Ucol1)
    if (u02 * u02 + u12 * u12 + u22 * u22 < 0.5) {
        u02 = u10 * u21 - u20 * u11;
        u12 = u20 * u01 - u00 * u21;
        u22 = u00 * u11 - u10 * u01;
    }

    // rot = V*U^T split: a_de = v_d0*u_e0 + v_d1*u_e1 ; b_de = v_d2*u_e2
    const double a00_ = v00*u00 + v01*u01, g00 = v02*u02;
    const double a01_ = v00*u10 + v01*u11, g01 = v02*u12;
    const double a02_ = v00*u20 + v01*u21, g02 = v02*u22;
    const double a10_ = v10*u00 + v11*u01, g10 = v12*u02;
    const double a11_ = v10*u10 + v11*u11, g11 = v12*u12;
    const double a12_ = v10*u20 + v11*u21, g12 = v12*u22;
    const double a20_ = v20*u00 + v21*u01, g20 = v22*u02;
    const double a21_ = v20*u10 + v21*u11, g21 = v22*u12;
    const double a22_ = v20*u20 + v21*u21, g22 = v22*u22;

    // det of rot_pos = a + g
    const double r00 = a00_ + g00, r01 = a01_ + g01, r02 = a02_ + g02;
    const double r10 = a10_ + g10, r11 = a11_ + g11, r12 = a12_ + g12;
    const double r20 = a20_ + g20, r21 = a21_ + g21, r22 = a22_ + g22;
    const double det = r00 * (r11 * r22 - r12 * r21)
                     - r01 * (r10 * r22 - r12 * r20)
                     + r02 * (r10 * r21 - r11 * r20);
    const double sgn = (det > 0.0) ? 1.0 : -1.0;

    const double R00 = a00_ + sgn * g00, R01 = a01_ + sgn * g01, R02 = a02_ + sgn * g02;
    const double R10 = a10_ + sgn * g10, R11 = a11_ + sgn * g11, R12 = a12_ + sgn * g12;
    const double R20 = a20_ + sgn * g20, R21 = a21_ + sgn * g21, R22 = a22_ + sgn * g22;

    const double t0 = -(R00 * cs0 + R01 * cs1 + R02 * cs2) + ct0;
    const double t1 = -(R10 * cs0 + R11 * cs1 + R12 * cs2) + ct1;
    const double t2 = -(R20 * cs0 + R21 * cs1 + R22 * cs2) + ct2;

    float* ro = out + (size_t)b * 9;
    ro[0] = (float)R00; ro[1] = (float)R01; ro[2] = (float)R02;
    ro[3] = (float)R10; ro[4] = (float)R11; ro[5] = (float)R12;
    ro[6] = (float)R20; ro[7] = (float)R21; ro[8] = (float)R22;
    float* to = out + (size_t)B * 9 + (size_t)b * 3;
    to[0] = (float)t0; to[1] = (float)t1; to[2] = (float)t2;
}

extern "C" void kernel_launch(void* const* d_in, const int* in_sizes, int n_in,
                              void* d_out, int out_size, void* d_ws, size_t ws_size,
                              hipStream_t stream) {
    const float* xyz_s   = (const float*)d_in[0];
    const float* wtgt    = (const float*)d_in[1];
    const float* weights = (const float*)d_in[2];
    const float* label   = (const float*)d_in[3];
    float* out = (float*)d_out;
    float* partials = (float*)d_ws;   // B*BPB*16 floats = 128 KB

    const int B = in_sizes[2] / N_PTS;   // weights has B*N elements

    dim3 grid1(BPB, B);
    ego_partial_kernel<<<grid1, TPB, 0, stream>>>(xyz_s, wtgt, weights, label, partials);
    ego_finalize_kernel<<<B, 64, 0, stream>>>(partials, out, B);
}

// Round 7
// 153.153 us; speedup vs baseline: 1.5327x; 1.0141x over previous
//
#include <hip/hip_runtime.h>
#include <math.h>

#define N_PTS 131072
#define BPB   64                 // blocks per batch (reduction chunks)
#define CHUNK 2048               // points per block
#define TPB   256
#define NACC  16                 // W, As[3], At[3], M[9]

typedef const __attribute__((address_space(1))) void gvoid_t;
typedef __attribute__((address_space(3))) void lvoid_t;

// ---------------- Kernel 1: LDS-staged streaming partial reduction --------
// Each wave stages 2 contiguous stream segments (channel-spread addresses)
// directly into LDS via global_load_lds; compute phase reads float4 from LDS.
__global__ __launch_bounds__(TPB) void ego_partial_kernel(
    const float* __restrict__ xyz_s,    // (B,3,N)
    const float* __restrict__ wtgt,     // (B,3,N)
    const float* __restrict__ weights,  // (B,1,N)
    const float* __restrict__ label,    // (B,1,N)
    float* __restrict__ partials)       // (B, BPB, 16)
{
    __shared__ __align__(16) float lds[8][CHUNK];   // 64 KB

    const int b    = blockIdx.y;
    const int c    = blockIdx.x;
    const int t    = threadIdx.x;
    const int wave = t >> 6;
    const int lane = t & 63;

    const size_t baseN = (size_t)b * N_PTS + (size_t)c * CHUNK;
    const size_t base3 = (size_t)b * 3 * N_PTS + (size_t)c * CHUNK;

    // wave-uniform stream selection (streams: 0=w 1=l 2..4=xs 5..7=xt)
    const float* g0;
    const float* g1;
    switch (wave) {
        case 0:  g0 = weights + baseN;           g1 = label + baseN;            break;
        case 1:  g0 = xyz_s + base3;             g1 = xyz_s + base3 + N_PTS;    break;
        case 2:  g0 = xyz_s + base3 + 2*N_PTS;   g1 = wtgt  + base3;            break;
        default: g0 = wtgt  + base3 + N_PTS;     g1 = wtgt  + base3 + 2*N_PTS;  break;
    }
    float* l0 = &lds[2 * wave][0];
    float* l1 = &lds[2 * wave + 1][0];

    // stage: 8 KB per stream per wave; 16B/lane per issue, 8 issues per stream
#pragma unroll
    for (int j = 0; j < 8; ++j) {
        const int off = j * 256 + lane * 4;     // floats (256 floats = 1 KB)
        __builtin_amdgcn_global_load_lds((gvoid_t*)(g0 + off),
                                         (lvoid_t*)(l0 + j * 256), 16, 0, 0);
    }
#pragma unroll
    for (int j = 0; j < 8; ++j) {
        const int off = j * 256 + lane * 4;
        __builtin_amdgcn_global_load_lds((gvoid_t*)(g1 + off),
                                         (lvoid_t*)(l1 + j * 256), 16, 0, 0);
    }
    __syncthreads();   // compiler drains vmcnt before barrier

    const float4* W4 = (const float4*)lds[0];
    const float4* L4 = (const float4*)lds[1];
    const float4* A0 = (const float4*)lds[2];
    const float4* A1 = (const float4*)lds[3];
    const float4* A2 = (const float4*)lds[4];
    const float4* B0 = (const float4*)lds[5];
    const float4* B1 = (const float4*)lds[6];
    const float4* B2 = (const float4*)lds[7];

    float acc[NACC];
#pragma unroll
    for (int i = 0; i < NACC; ++i) acc[i] = 0.0f;

#pragma unroll
    for (int k = 0; k < CHUNK / 4 / TPB; ++k) {   // 2 iterations
        const int i = t + k * TPB;
        const float4 wv = W4[i];
        const float4 lv = L4[i];
        const float4 a0 = A0[i], a1 = A1[i], a2 = A2[i];
        const float4 b0 = B0[i], b1 = B1[i], b2 = B2[i];

#define ACCUM(C)                                              \
        {                                                     \
            const float w  = wv.C * fabsf(lv.C - 1.0f);       \
            const float s0 = a0.C, s1 = a1.C, s2 = a2.C;      \
            const float t0 = b0.C, t1 = b1.C, t2 = b2.C;      \
            acc[0] += w;                                      \
            const float ws0 = w * s0, ws1 = w * s1, ws2 = w * s2; \
            acc[1] += ws0;  acc[2] += ws1;  acc[3] += ws2;    \
            acc[4] += w * t0; acc[5] += w * t1; acc[6] += w * t2; \
            acc[7]  += ws0 * t0; acc[8]  += ws0 * t1; acc[9]  += ws0 * t2; \
            acc[10] += ws1 * t0; acc[11] += ws1 * t1; acc[12] += ws1 * t2; \
            acc[13] += ws2 * t0; acc[14] += ws2 * t1; acc[15] += ws2 * t2; \
        }
        ACCUM(x) ACCUM(y) ACCUM(z) ACCUM(w)
#undef ACCUM
    }

    // wave-level reduce (64 lanes)
#pragma unroll
    for (int i = 0; i < NACC; ++i) {
        float v = acc[i];
#pragma unroll
        for (int off = 32; off > 0; off >>= 1)
            v += __shfl_down(v, off, 64);
        acc[i] = v;
    }

    __syncthreads();   // done reading lds[][]; safe to reuse for reduction
    float* red = (float*)lds;   // [4][NACC]
    if (lane == 0) {
#pragma unroll
        for (int i = 0; i < NACC; ++i) red[wave * NACC + i] = acc[i];
    }
    __syncthreads();

    if (t < NACC) {
        float v = 0.0f;
#pragma unroll
        for (int wv_ = 0; wv_ < TPB / 64; ++wv_) v += red[wv_ * NACC + t];
        partials[((size_t)b * BPB + c) * NACC + t] = v;
    }
}

// ---------------- Kernel 2: final reduce + scratch-free 3x3 SVD ----------
__global__ __launch_bounds__(64) void ego_finalize_kernel(
    const float* __restrict__ partials,  // (B, BPB, 16)
    float* __restrict__ out,             // rot (B,3,3) then translation (B,3,1)
    int B)
{
    const int b = blockIdx.x;
    const int t = threadIdx.x;   // 0..63 == BPB

    double acc[NACC];
    const float* p = partials + ((size_t)b * BPB + t) * NACC;
#pragma unroll
    for (int i = 0; i < NACC; ++i) acc[i] = (double)p[i];

#pragma unroll
    for (int i = 0; i < NACC; ++i) {
        double v = acc[i];
#pragma unroll
        for (int off = 32; off > 0; off >>= 1)
            v += __shfl_down(v, off, 64);
        acc[i] = v;
    }

    if (t != 0) return;

    // ---- all-scalar solve: no arrays, no dynamic indexing, no scratch ----
    const double W     = acc[0];
    const double denom = W + 1e-6;
    const double cs0 = acc[1] / denom, cs1 = acc[2] / denom, cs2 = acc[3] / denom;
    const double ct0 = acc[4] / denom, ct1 = acc[5] / denom, ct2 = acc[6] / denom;
    const double f   = 2.0 - W / denom;

    const double c00 = acc[7]  / denom - cs0 * ct0 * f;
    const double c01 = acc[8]  / denom - cs0 * ct1 * f;
    const double c02 = acc[9]  / denom - cs0 * ct2 * f;
    const double c10 = acc[10] / denom - cs1 * ct0 * f;
    const double c11 = acc[11] / denom - cs1 * ct1 * f;
    const double c12 = acc[12] / denom - cs1 * ct2 * f;
    const double c20 = acc[13] / denom - cs2 * ct0 * f;
    const double c21 = acc[14] / denom - cs2 * ct1 * f;
    const double c22 = acc[15] / denom - cs2 * ct2 * f;

    // Bm = cov^T cov (symmetric, 6 scalars)
    double b00 = c00*c00 + c10*c10 + c20*c20;
    double b01 = c00*c01 + c10*c11 + c20*c21;
    double b02 = c00*c02 + c10*c12 + c20*c22;
    double b11 = c01*c01 + c11*c11 + c21*c21;
    double b12 = c01*c02 + c11*c12 + c21*c22;
    double b22 = c02*c02 + c12*c12 + c22*c22;

    double v00 = 1, v01 = 0, v02 = 0;
    double v10 = 0, v11 = 1, v12 = 0;
    double v20 = 0, v21 = 0, v22 = 1;

#define JROT(bpp, bqq, bpq, bkp, bkq, vp0, vp1, vp2, vq0, vq1, vq2)   \
    if (fabs(bpq) > 1e-30) {                                          \
        const double tau = (bqq - bpp) / (2.0 * bpq);                 \
        const double jt  = (tau >= 0.0 ? 1.0 : -1.0) /                \
                           (fabs(tau) + sqrt(1.0 + tau * tau));       \
        const double jc  = 1.0 / sqrt(1.0 + jt * jt);                 \
        const double js  = jt * jc;                                   \
        bpp -= jt * bpq; bqq += jt * bpq; bpq = 0.0;                  \
        { const double kp = bkp, kq = bkq;                            \
          bkp = jc * kp - js * kq; bkq = js * kp + jc * kq; }         \
        { double x;                                                   \
          x = vp0; vp0 = jc * x - js * vq0; vq0 = js * x + jc * vq0;  \
          x = vp1; vp1 = jc * x - js * vq1; vq1 = js * x + jc * vq1;  \
          x = vp2; vp2 = jc * x - js * vq2; vq2 = js * x + jc * vq2; }\
    }

#pragma unroll
    for (int sweep = 0; sweep < 6; ++sweep) {
        JROT(b00, b11, b01, b02, b12, v00, v10, v20, v01, v11, v21)
        JROT(b00, b22, b02, b01, b12, v00, v10, v20, v02, v12, v22)
        JROT(b11, b22, b12, b01, b02, v01, v11, v21, v02, v12, v22)
    }
#undef JROT

    double l0 = b00, l1 = b11, l2 = b22;
#define CSWAP(la, lb, a0, a1, a2, q0, q1, q2)                         \
    if (lb > la) { double x;                                          \
        x = la; la = lb; lb = x;                                      \
        x = a0; a0 = q0; q0 = x;                                      \
        x = a1; a1 = q1; q1 = x;                                      \
        x = a2; a2 = q2; q2 = x; }
    CSWAP(l0, l1, v00, v10, v20, v01, v11, v21)
    CSWAP(l0, l2, v00, v10, v20, v02, v12, v22)
    CSWAP(l1, l2, v01, v11, v21, v02, v12, v22)
#undef CSWAP

#define MAKEU(vc0, vc1, vc2, u0, u1, u2)                              \
    double u0 = c00 * vc0 + c01 * vc1 + c02 * vc2;                    \
    double u1 = c10 * vc0 + c11 * vc1 + c12 * vc2;                    \
    double u2 = c20 * vc0 + c21 * vc1 + c22 * vc2;                    \
    { const double nn = sqrt(u0 * u0 + u1 * u1 + u2 * u2);            \
      const double r = (nn > 1e-150) ? 1.0 / nn : 0.0;                \
      u0 *= r; u1 *= r; u2 *= r; }
    MAKEU(v00, v10, v20, u00, u10, u20)
    MAKEU(v01, v11, v21, u01, u11, u21)
    MAKEU(v02, v12, v22, u02, u12, u22)
#undef MAKEU
    if (u02 * u02 + u12 * u12 + u22 * u22 < 0.5) {
        u02 = u10 * u21 - u20 * u11;
        u12 = u20 * u01 - u00 * u21;
        u22 = u00 * u11 - u10 * u01;
    }

    const double a00_ = v00*u00 + v01*u01, g00 = v02*u02;
    const double a01_ = v00*u10 + v01*u11, g01 = v02*u12;
    const double a02_ = v00*u20 + v01*u21, g02 = v02*u22;
    const double a10_ = v10*u00 + v11*u01, g10 = v12*u02;
    const double a11_ = v10*u10 + v11*u11, g11 = v12*u12;
    const double a12_ = v10*u20 + v11*u21, g12 = v12*u22;
    const double a20_ = v20*u00 + v21*u01, g20 = v22*u02;
    const double a21_ = v20*u10 + v21*u11, g21 = v22*u12;
    const double a22_ = v20*u20 + v21*u21, g22 = v22*u22;

    const double r00 = a00_ + g00, r01 = a01_ + g01, r02 = a02_ + g02;
    const double r10 = a10_ + g10, r11 = a11_ + g11, r12 = a12_ + g12;
    const double r20 = a20_ + g20, r21 = a21_ + g21, r22 = a22_ + g22;
    const double det = r00 * (r11 * r22 - r12 * r21)
                     - r01 * (r10 * r22 - r12 * r20)
                     + r02 * (r10 * r21 - r11 * r20);
    const double sgn = (det > 0.0) ? 1.0 : -1.0;

    const double R00 = a00_ + sgn * g00, R01 = a01_ + sgn * g01, R02 = a02_ + sgn * g02;
    const double R10 = a10_ + sgn * g10, R11 = a11_ + sgn * g11, R12 = a12_ + sgn * g12;
    const double R20 = a20_ + sgn * g20, R21 = a21_ + sgn * g21, R22 = a22_ + sgn * g22;

    const double t0 = -(R00 * cs0 + R01 * cs1 + R02 * cs2) + ct0;
    const double t1 = -(R10 * cs0 + R11 * cs1 + R12 * cs2) + ct1;
    const double t2 = -(R20 * cs0 + R21 * cs1 + R22 * cs2) + ct2;

    float* ro = out + (size_t)b * 9;
    ro[0] = (float)R00; ro[1] = (float)R01; ro[2] = (float)R02;
    ro[3] = (float)R10; ro[4] = (float)R11; ro[5] = (float)R12;
    ro[6] = (float)R20; ro[7] = (float)R21; ro[8] = (float)R22;
    float* to = out + (size_t)B * 9 + (size_t)b * 3;
    to[0] = (float)t0; to[1] = (float)t1; to[2] = (float)t2;
}

extern "C" void kernel_launch(void* const* d_in, const int* in_sizes, int n_in,
                              void* d_out, int out_size, void* d_ws, size_t ws_size,
                              hipStream_t stream) {
    const float* xyz_s   = (const float*)d_in[0];
    const float* wtgt    = (const float*)d_in[1];
    const float* weights = (const float*)d_in[2];
    const float* label   = (const float*)d_in[3];
    float* out = (float*)d_out;
    float* partials = (float*)d_ws;   // B*BPB*16 floats = 128 KB

    const int B = in_sizes[2] / N_PTS;   // weights has B*N elements

    dim3 grid1(BPB, B);
    ego_partial_kernel<<<grid1, TPB, 0, stream>>>(xyz_s, wtgt, weights, label, partials);
    ego_finalize_kernel<<<B, 64, 0, stream>>>(partials, out, B);
}